// Round 1
// baseline (229.145 us; speedup 1.0000x reference)
//
#include <hip/hip_runtime.h>
#include <hip/hip_bf16.h>

#define SPK 1024
#define UTT 64
#define DIM 256
#define EPSV 1e-5f
#define NROW (SPK * UTT)

typedef __attribute__((ext_vector_type(8))) short short8;   // 8 bf16 (4 VGPRs)
typedef __attribute__((ext_vector_type(4))) float f32x4;    // MFMA accumulator

__device__ __forceinline__ unsigned short f2bf(float f) {
    unsigned int u = __builtin_bit_cast(unsigned int, f);
    u += 0x7fffu + ((u >> 16) & 1u);          // round-to-nearest-even
    return (unsigned short)(u >> 16);
}

// K1: per-speaker sum over utterances + normalized inclusive centroid (bf16).
// c_incl = csum / (||csum|| + U*eps)   (algebraically == (csum/U)/(||csum/U||+eps))
__global__ void k_centroid(const float* __restrict__ x,
                           float* __restrict__ csum,
                           unsigned short* __restrict__ cincl) {
    int s = blockIdx.x, t = threadIdx.x;     // 256 threads = one d each
    const float* base = x + (size_t)s * UTT * DIM + t;
    float acc = 0.f;
#pragma unroll 16
    for (int u = 0; u < UTT; ++u) acc += base[(size_t)u * DIM];
    csum[s * DIM + t] = acc;
    float v = acc * acc;
#pragma unroll
    for (int o = 1; o < 64; o <<= 1) v += __shfl_xor(v, o);
    __shared__ float red[4];
    if ((t & 63) == 0) red[t >> 6] = v;
    __syncthreads();
    float n2 = red[0] + red[1] + red[2] + red[3];
    float inv = 1.f / (sqrtf(n2) + UTT * EPSV);
    cincl[s * DIM + t] = f2bf(acc * inv);
}

// K2: one wave per row. Row norm, leave-one-out centroid norm, sim_excl (fp32),
// writes e_n (bf16) and pre-scaled diagonal logit w*sim_excl+b.
__global__ void k_rows(const float* __restrict__ x,
                       const float* __restrict__ csum,
                       unsigned short* __restrict__ en,
                       float* __restrict__ texcl,
                       const float* __restrict__ wp,
                       const float* __restrict__ bp) {
    int wave = threadIdx.x >> 6, lane = threadIdx.x & 63;
    int row = blockIdx.x * 4 + wave;
    int s = row >> 6;
    const float4* xr = (const float4*)(x + (size_t)row * DIM);
    const float4* cr = (const float4*)(csum + (size_t)s * DIM);
    float4 xv = xr[lane];
    float4 cv = cr[lane];
    float ex = cv.x - xv.x, ey = cv.y - xv.y, ez = cv.z - xv.z, ew = cv.w - xv.w;
    float sx = xv.x * xv.x + xv.y * xv.y + xv.z * xv.z + xv.w * xv.w;
    float se = ex * ex + ey * ey + ez * ez + ew * ew;
    float sc = xv.x * ex + xv.y * ey + xv.z * ez + xv.w * ew;
#pragma unroll
    for (int o = 1; o < 64; o <<= 1) {
        sx += __shfl_xor(sx, o);
        se += __shfl_xor(se, o);
        sc += __shfl_xor(sc, o);
    }
    float inv_e = 1.f / (sqrtf(sx) + EPSV);
    ushort4 ob;
    ob.x = f2bf(xv.x * inv_e); ob.y = f2bf(xv.y * inv_e);
    ob.z = f2bf(xv.z * inv_e); ob.w = f2bf(xv.w * inv_e);
    *(ushort4*)(en + (size_t)row * DIM + lane * 4) = ob;
    if (lane == 0) {
        // sim_excl = (x . (csum-x)) / ((||x||+eps) * (||csum-x|| + 63*eps))
        float sim = sc / ((sqrtf(sx) + EPSV) * (sqrtf(se) + (UTT - 1) * EPSV));
        texcl[row] = sim * wp[0] + bp[0];
    }
}

// K3: block = one speaker (64 rows), 4 waves x 16 rows. MFMA 16x16x32 bf16,
// A (e_n rows) in registers, B (c_incl) staged via LDS in 64-col chunks,
// fused online logsumexp; diagonal column replaced by pre-scaled excl logit.
__global__ __launch_bounds__(256)
void k_main(const unsigned short* __restrict__ en,
            const unsigned short* __restrict__ cincl,
            const float* __restrict__ texcl,
            const float* __restrict__ wp,
            const float* __restrict__ bp,
            float* __restrict__ out) {
    // row pitch 264 bf16 (=132 words): lanes spread evenly over banks -> b128 floor
    __shared__ unsigned short Bs[64][DIM + 8];
    int s = blockIdx.x;
    int tid = threadIdx.x;
    int wave = tid >> 6, lane = tid & 63;
    int quad = lane >> 4, lx = lane & 15;
    float w = wp[0], b = bp[0];

    // A fragments: A[m=lane&15][k=quad*8+j] per ktile (16x16x32 bf16 layout)
    const unsigned short* arow = en + (size_t)(s * UTT + wave * 16 + lx) * DIM;
    short8 afrag[8];
#pragma unroll
    for (int kt = 0; kt < 8; ++kt)
        afrag[kt] = *(const short8*)(arow + kt * 32 + quad * 8);

    // pre-scaled excl logits for my 4 rows (C-layout rows: quad*4 + r)
    float tex[4];
#pragma unroll
    for (int r = 0; r < 4; ++r)
        tex[r] = texcl[s * UTT + wave * 16 + quad * 4 + r];

    float m[4], l[4];
#pragma unroll
    for (int r = 0; r < 4; ++r) { m[r] = -3.0e38f; l[r] = 0.f; }

    int srow = tid >> 2, part = tid & 3;   // staging: 4 threads per B row
    for (int chunk = 0; chunk < SPK / 64; ++chunk) {
        __syncthreads();
        const unsigned short* brow = cincl + (size_t)(chunk * 64 + srow) * DIM + part * 64;
        unsigned short* dst = &Bs[srow][part * 64];
#pragma unroll
        for (int j = 0; j < 8; ++j)
            *(short8*)(dst + j * 8) = *(const short8*)(brow + j * 8);
        __syncthreads();
#pragma unroll
        for (int sub = 0; sub < 4; ++sub) {
            f32x4 acc = {0.f, 0.f, 0.f, 0.f};
#pragma unroll
            for (int kt = 0; kt < 8; ++kt) {
                short8 bfrag = *(const short8*)(&Bs[sub * 16 + lx][kt * 32 + quad * 8]);
                acc = __builtin_amdgcn_mfma_f32_16x16x32_bf16(afrag[kt], bfrag, acc, 0, 0, 0);
            }
            bool diag = (chunk * 64 + sub * 16 + lx) == s;
#pragma unroll
            for (int r = 0; r < 4; ++r) {
                float v = diag ? tex[r] : fmaf(acc[r], w, b);
                float nm = fmaxf(m[r], v);
                l[r] = l[r] * __expf(m[r] - nm) + __expf(v - nm);
                m[r] = nm;
            }
        }
    }
    // combine (m,l) across the 16 lanes holding each row's columns
#pragma unroll
    for (int o = 1; o < 16; o <<= 1) {
#pragma unroll
        for (int r = 0; r < 4; ++r) {
            float mo = __shfl_xor(m[r], o);
            float lo = __shfl_xor(l[r], o);
            float nm = fmaxf(m[r], mo);
            l[r] = l[r] * __expf(m[r] - nm) + lo * __expf(mo - nm);
            m[r] = nm;
        }
    }
    // loss contribution: sum over rows of (lse - target_logit)
    float contrib = 0.f;
    if (lx == 0) {
#pragma unroll
        for (int r = 0; r < 4; ++r)
            contrib += (m[r] + __logf(l[r])) - tex[r];
    }
#pragma unroll
    for (int o = 1; o < 64; o <<= 1) contrib += __shfl_xor(contrib, o);
    if (lane == 0) atomicAdd(out, contrib * (1.f / NROW));
}

extern "C" void kernel_launch(void* const* d_in, const int* in_sizes, int n_in,
                              void* d_out, int out_size, void* d_ws, size_t ws_size,
                              hipStream_t stream) {
    const float* x  = (const float*)d_in[0];
    const float* wp = (const float*)d_in[1];
    const float* bp = (const float*)d_in[2];
    char* ws = (char*)d_ws;
    float* csum           = (float*)ws;                                    // 1 MB
    unsigned short* cincl = (unsigned short*)(ws + (1u << 20));            // 0.5 MB
    float* texcl          = (float*)(ws + (1u << 20) + (1u << 19));        // 256 KB
    unsigned short* en    = (unsigned short*)(ws + (1u << 20) + (1u << 19) + (1u << 18)); // 32 MB
    float* out = (float*)d_out;

    hipMemsetAsync(d_out, 0, sizeof(float), stream);
    k_centroid<<<SPK, DIM, 0, stream>>>(x, csum, cincl);
    k_rows<<<NROW / 4, 256, 0, stream>>>(x, csum, en, texcl, wp, bp);
    k_main<<<SPK, 256, 0, stream>>>(en, cincl, texcl, wp, bp, out);
}

// Round 2
// 193.217 us; speedup vs baseline: 1.1859x; 1.1859x over previous
//
#include <hip/hip_runtime.h>

#define SPK 1024
#define UTT 64
#define DIM 256
#define EPSV 1e-5f
#define NROW (SPK * UTT)

typedef __attribute__((ext_vector_type(8))) short short8;   // 8 bf16 (4 VGPRs)
typedef __attribute__((ext_vector_type(4))) float f32x4;    // MFMA accumulator

__device__ __forceinline__ unsigned short f2bf(float f) {
    unsigned int u = __builtin_bit_cast(unsigned int, f);
    u += 0x7fffu + ((u >> 16) & 1u);          // round-to-nearest-even
    return (unsigned short)(u >> 16);
}

// K1: fused centroid + per-row normalize. One block (256 thr) per speaker.
// Reads x once (float4), keeps csum in LDS; phase-B re-reads are L2-hot.
__global__ __launch_bounds__(256)
void k_prep(const float* __restrict__ x,
            unsigned short* __restrict__ cincl,
            unsigned short* __restrict__ en,
            float* __restrict__ texcl,
            const float* __restrict__ wp, const float* __restrict__ bp) {
    __shared__ float4 sc4[256];
    __shared__ float4 cs4[64];
    __shared__ float sccs;
    int s = blockIdx.x, tid = threadIdx.x;
    int dq = tid & 63, ug = tid >> 6;
    const float4* x4 = (const float4*)(x + (size_t)s * UTT * DIM);

    // Phase A: column sums (csum), inclusive centroid
    float4 p = {0.f, 0.f, 0.f, 0.f};
#pragma unroll
    for (int i = 0; i < 16; ++i) {
        float4 v = x4[(ug * 16 + i) * 64 + dq];
        p.x += v.x; p.y += v.y; p.z += v.z; p.w += v.w;
    }
    sc4[tid] = p;
    __syncthreads();
    if (tid < 64) {
        float4 a = sc4[dq], b2 = sc4[64 + dq], c = sc4[128 + dq], d = sc4[192 + dq];
        float4 cs = {a.x + b2.x + c.x + d.x, a.y + b2.y + c.y + d.y,
                     a.z + b2.z + c.z + d.z, a.w + b2.w + c.w + d.w};
        cs4[dq] = cs;
        float s2 = cs.x * cs.x + cs.y * cs.y + cs.z * cs.z + cs.w * cs.w;
#pragma unroll
        for (int o = 1; o < 64; o <<= 1) s2 += __shfl_xor(s2, o);
        if (tid == 0) sccs = s2;
        // c_incl = (csum/U)/(||csum/U||+eps) == csum/(||csum|| + U*eps)
        float inv = 1.f / (sqrtf(s2) + UTT * EPSV);
        ushort4 ob = {f2bf(cs.x * inv), f2bf(cs.y * inv),
                      f2bf(cs.z * inv), f2bf(cs.w * inv)};
        *(ushort4*)(cincl + (size_t)s * DIM + dq * 4) = ob;
    }
    __syncthreads();
    float scc = sccs;
    float w = wp[0], b = bp[0];
    int wave = tid >> 6, lane = tid & 63;

    // Phase B: one wave per row (16 rows each): e_n + excl-centroid logit
    for (int r0 = 0; r0 < 16; ++r0) {
        int row = wave * 16 + r0;
        float4 xv = x4[row * 64 + lane];
        float4 cv = cs4[lane];
        float sx = xv.x * xv.x + xv.y * xv.y + xv.z * xv.z + xv.w * xv.w;
        float sc = xv.x * cv.x + xv.y * cv.y + xv.z * cv.z + xv.w * cv.w;
#pragma unroll
        for (int o = 1; o < 64; o <<= 1) {
            sx += __shfl_xor(sx, o);
            sc += __shfl_xor(sc, o);
        }
        float inv = 1.f / (sqrtf(sx) + EPSV);
        ushort4 ob = {f2bf(xv.x * inv), f2bf(xv.y * inv),
                      f2bf(xv.z * inv), f2bf(xv.w * inv)};
        *(ushort4*)(en + (size_t)(s * UTT + row) * DIM + lane * 4) = ob;
        if (lane == 0) {
            // sim_excl = x.(csum-x) / ((||x||+eps)(||csum-x||+63eps))
            float num = sc - sx;
            float e2 = fmaxf(scc - 2.f * sc + sx, 0.f);
            float sim = num / ((sqrtf(sx) + EPSV) * (sqrtf(e2) + (UTT - 1) * EPSV));
            texcl[s * UTT + row] = fmaf(sim, w, b);
        }
    }
}

// K2: block = 4 speakers, wave = 1 speaker (M=64 rows in registers, all N=1024).
// B (cincl) staged per 64-col chunk via global_load_lds into lane-contiguous
// swizzled layout -> conflict-free ds_read_b128. Fixed-max online softmax.
__global__ __launch_bounds__(256)
void k_main(const unsigned short* __restrict__ en,
            const unsigned short* __restrict__ cincl,
            const float* __restrict__ texcl,
            const float* __restrict__ wp, const float* __restrict__ bp,
            float* __restrict__ out) {
    // slot (p = sub*8+kt): 64 lanes x 16B, LDS addr = p*1024 + lane*16
    __shared__ unsigned short Bs[32 * 64 * 8];   // 32 KB
    int tid = threadIdx.x, wave = tid >> 6, lane = tid & 63;
    int quad = lane >> 4, lx = lane & 15;
    int sw = blockIdx.x * 4 + wave;              // this wave's speaker
    float w = wp[0], b = bp[0];
    float M = fabsf(w) * 1.0625f + b;            // >= any logit (sim <= ~1)

    // A fragments: all 64 rows of speaker sw. A[m=lx][k=quad*8+j] per (mt,kt).
    const unsigned short* abase = en + (size_t)sw * UTT * DIM;
    short8 af[4][8];
#pragma unroll
    for (int mt = 0; mt < 4; ++mt)
#pragma unroll
        for (int kt = 0; kt < 8; ++kt)
            af[mt][kt] = *(const short8*)(abase + (mt * 16 + lx) * DIM + kt * 32 + quad * 8);

    float l[16];
#pragma unroll
    for (int i = 0; i < 16; ++i) l[i] = 0.f;

    for (int chunk = 0; chunk < 16; ++chunk) {
        // stage 64 cols x 256 k of cincl, swizzled; wave w stages slots w*8..w*8+7
#pragma unroll
        for (int i = 0; i < 8; ++i) {
            int p = wave * 8 + i;
            int sub = p >> 3, kt = p & 7;
            const unsigned short* g = cincl +
                (size_t)(chunk * 64 + sub * 16 + lx) * DIM + kt * 32 + quad * 8;
            __builtin_amdgcn_global_load_lds(
                (const __attribute__((address_space(1))) void*)g,
                (__attribute__((address_space(3))) void*)(Bs + p * 512), 16, 0, 0);
        }
        __syncthreads();
#pragma unroll
        for (int nt = 0; nt < 4; ++nt) {
            f32x4 acc[4] = {{0.f,0.f,0.f,0.f},{0.f,0.f,0.f,0.f},
                            {0.f,0.f,0.f,0.f},{0.f,0.f,0.f,0.f}};
#pragma unroll
            for (int kt = 0; kt < 8; ++kt) {
                short8 bf = *(const short8*)(Bs + ((nt * 8 + kt) * 64 + lane) * 8);
                acc[0] = __builtin_amdgcn_mfma_f32_16x16x32_bf16(af[0][kt], bf, acc[0], 0, 0, 0);
                acc[1] = __builtin_amdgcn_mfma_f32_16x16x32_bf16(af[1][kt], bf, acc[1], 0, 0, 0);
                acc[2] = __builtin_amdgcn_mfma_f32_16x16x32_bf16(af[2][kt], bf, acc[2], 0, 0, 0);
                acc[3] = __builtin_amdgcn_mfma_f32_16x16x32_bf16(af[3][kt], bf, acc[3], 0, 0, 0);
            }
            int col = chunk * 64 + nt * 16 + lx;
            bool diag = (col == sw);
#pragma unroll
            for (int mt = 0; mt < 4; ++mt)
#pragma unroll
                for (int r = 0; r < 4; ++r) {
                    float v = fmaf(acc[mt][r], w, b);
                    float e = __expf(v - M);
                    l[mt * 4 + r] += diag ? 0.f : e;
                }
        }
        __syncthreads();
    }

    // sum l over the 16 lx lanes (cols); rows live in (quad, mt, r)
#pragma unroll
    for (int o = 1; o < 16; o <<= 1)
#pragma unroll
        for (int i = 0; i < 16; ++i) l[i] += __shfl_xor(l[i], o);

    float contrib = 0.f;
    if (lx == 0) {
#pragma unroll
        for (int mt = 0; mt < 4; ++mt)
#pragma unroll
            for (int r = 0; r < 4; ++r) {
                int row = mt * 16 + quad * 4 + r;
                float tex = texcl[sw * UTT + row];        // fp32 diag logit
                float lsum = l[mt * 4 + r] + __expf(tex - M);
                contrib += (M + __logf(lsum)) - tex;      // lse - target
            }
    }
#pragma unroll
    for (int o = 1; o < 64; o <<= 1) contrib += __shfl_xor(contrib, o);
    if (lane == 0) atomicAdd(out, contrib * (1.f / NROW));
}

extern "C" void kernel_launch(void* const* d_in, const int* in_sizes, int n_in,
                              void* d_out, int out_size, void* d_ws, size_t ws_size,
                              hipStream_t stream) {
    const float* x  = (const float*)d_in[0];
    const float* wp = (const float*)d_in[1];
    const float* bp = (const float*)d_in[2];
    char* ws = (char*)d_ws;
    unsigned short* cincl = (unsigned short*)ws;                  // 512 KB
    float* texcl          = (float*)(ws + (1u << 19));            // 256 KB
    unsigned short* en    = (unsigned short*)(ws + (1u << 19) + (1u << 18)); // 32 MB
    float* out = (float*)d_out;

    hipMemsetAsync(d_out, 0, sizeof(float), stream);
    k_prep<<<SPK, 256, 0, stream>>>(x, cincl, en, texcl, wp, bp);
    k_main<<<SPK / 4, 256, 0, stream>>>(en, cincl, texcl, wp, bp, out);
}

// Round 3
// 186.586 us; speedup vs baseline: 1.2281x; 1.0355x over previous
//
#include <hip/hip_runtime.h>

#define SPK 1024
#define UTT 64
#define DIM 256
#define EPSV 1e-5f
#define NROW (SPK * UTT)

typedef __attribute__((ext_vector_type(8))) short short8;   // 8 bf16 (4 VGPRs)
typedef __attribute__((ext_vector_type(4))) float f32x4;    // MFMA accumulator

__device__ __forceinline__ unsigned short f2bf(float f) {
    unsigned int u = __builtin_bit_cast(unsigned int, f);
    u += 0x7fffu + ((u >> 16) & 1u);          // round-to-nearest-even
    return (unsigned short)(u >> 16);
}

// K1: one block (256 thr) per speaker. Phase A: csum + c_incl (bf16) + ||csum||^2.
// Phase B: 4 lanes per row (quad-reduce, 2 shfl steps), x rows cached in regs,
// writes e_n (bf16) and pre-scaled diagonal logit texcl = w*sim_excl + b.
__global__ __launch_bounds__(256)
void k_prep(const float* __restrict__ x,
            unsigned short* __restrict__ cincl,
            unsigned short* __restrict__ en,
            float* __restrict__ texcl,
            const float* __restrict__ wp, const float* __restrict__ bp) {
    __shared__ float4 sc4[256];
    __shared__ float4 cs4[64];
    __shared__ float sccs;
    int s = blockIdx.x, tid = threadIdx.x;
    int dq = tid & 63, ug = tid >> 6;
    const float4* x4 = (const float4*)(x + (size_t)s * UTT * DIM);

    // Phase A: column sums over the 64 utterances (coalesced 1KB/instr)
    float4 p = {0.f, 0.f, 0.f, 0.f};
#pragma unroll
    for (int i = 0; i < 16; ++i) {
        float4 v = x4[(ug * 16 + i) * 64 + dq];
        p.x += v.x; p.y += v.y; p.z += v.z; p.w += v.w;
    }
    sc4[tid] = p;
    __syncthreads();
    if (tid < 64) {
        float4 a = sc4[dq], b2 = sc4[64 + dq], c = sc4[128 + dq], d = sc4[192 + dq];
        float4 cs = {a.x + b2.x + c.x + d.x, a.y + b2.y + c.y + d.y,
                     a.z + b2.z + c.z + d.z, a.w + b2.w + c.w + d.w};
        cs4[dq] = cs;
        float s2 = cs.x * cs.x + cs.y * cs.y + cs.z * cs.z + cs.w * cs.w;
#pragma unroll
        for (int o = 1; o < 64; o <<= 1) s2 += __shfl_xor(s2, o);
        if (tid == 0) sccs = s2;
        // c_incl = (csum/U)/(||csum/U||+eps) == csum/(||csum|| + U*eps)
        float inv = 1.f / (sqrtf(s2) + UTT * EPSV);
        ushort4 ob = {f2bf(cs.x * inv), f2bf(cs.y * inv),
                      f2bf(cs.z * inv), f2bf(cs.w * inv)};
        *(ushort4*)(cincl + (size_t)s * DIM + dq * 4) = ob;
    }
    __syncthreads();
    float scc = sccs;
    float w = wp[0], b = bp[0];

    // Phase B: row = tid>>2 (64 rows), sub = tid&3 (4 lanes per row).
    int row = tid >> 2, sub = tid & 3;
    const float4* xr = x4 + row * 64;
    float4 xv[16];
    float sx = 0.f, sc = 0.f;
#pragma unroll
    for (int i = 0; i < 16; ++i) {
        float4 v = xr[i * 4 + sub];
        float4 cv = cs4[i * 4 + sub];
        xv[i] = v;
        sx += v.x * v.x + v.y * v.y + v.z * v.z + v.w * v.w;
        sc += v.x * cv.x + v.y * cv.y + v.z * cv.z + v.w * cv.w;
    }
    // quad reduce: all 4 lanes of the row end up with the totals
    sx += __shfl_xor(sx, 1); sx += __shfl_xor(sx, 2);
    sc += __shfl_xor(sc, 1); sc += __shfl_xor(sc, 2);
    float nx = sqrtf(sx);
    float inv = 1.f / (nx + EPSV);
    unsigned short* er = en + (size_t)(s * UTT + row) * DIM;
#pragma unroll
    for (int i = 0; i < 16; ++i) {
        ushort4 ob = {f2bf(xv[i].x * inv), f2bf(xv[i].y * inv),
                      f2bf(xv[i].z * inv), f2bf(xv[i].w * inv)};
        *(ushort4*)(er + (i * 4 + sub) * 4) = ob;
    }
    if (sub == 0) {
        // sim_excl = x.(csum-x) / ((||x||+eps)(||csum-x||+63eps))
        float num = sc - sx;
        float e2 = fmaxf(scc - 2.f * sc + sx, 0.f);
        float sim = num / ((nx + EPSV) * (sqrtf(e2) + (UTT - 1) * EPSV));
        texcl[s * UTT + row] = fmaf(sim, w, b);
    }
}

// K2: block = 1 speaker (4 waves); wave = all 64 rows x its 256-col slice.
// A fragments resident in regs; B read straight from L2-resident cincl
// (no LDS staging, no barriers in the hot loop). Fixed-max softmax; the
// 4 waves' partial sums combine via LDS at the end.
__global__ __launch_bounds__(256, 2)
void k_main(const unsigned short* __restrict__ en,
            const unsigned short* __restrict__ cincl,
            const float* __restrict__ texcl,
            const float* __restrict__ wp, const float* __restrict__ bp,
            float* __restrict__ out) {
    __shared__ float sl[4][UTT];
    int s = blockIdx.x, tid = threadIdx.x;
    int wave = tid >> 6, lane = tid & 63;
    int quad = lane >> 4, lx = lane & 15;
    float w = wp[0], b = bp[0];
    float M = fabsf(w) * 1.0625f + b;            // >= any logit (|sim| <= ~1)

    // A fragments: speaker s, all 64 rows. A[m=lx][k=quad*8+j] per (mt,kt).
    const unsigned short* abase = en + (size_t)s * UTT * DIM;
    short8 af[4][8];
#pragma unroll
    for (int mt = 0; mt < 4; ++mt)
#pragma unroll
        for (int kt = 0; kt < 8; ++kt)
            af[mt][kt] = *(const short8*)(abase + (mt * 16 + lx) * DIM + kt * 32 + quad * 8);

    float l[16];
#pragma unroll
    for (int i = 0; i < 16; ++i) l[i] = 0.f;

    int col0 = wave * 256;
    // prefetch nt=0 B fragments
    short8 bf[8];
    {
        const unsigned short* bc = cincl + (size_t)(col0 + lx) * DIM + quad * 8;
#pragma unroll
        for (int kt = 0; kt < 8; ++kt) bf[kt] = *(const short8*)(bc + kt * 32);
    }
    for (int nt = 0; nt < 16; ++nt) {
        short8 cur[8];
#pragma unroll
        for (int kt = 0; kt < 8; ++kt) cur[kt] = bf[kt];
        if (nt < 15) {   // prefetch next tile while current computes
            const unsigned short* bc = cincl + (size_t)(col0 + (nt + 1) * 16 + lx) * DIM + quad * 8;
#pragma unroll
            for (int kt = 0; kt < 8; ++kt) bf[kt] = *(const short8*)(bc + kt * 32);
        }
        f32x4 acc[4] = {{0.f,0.f,0.f,0.f},{0.f,0.f,0.f,0.f},
                        {0.f,0.f,0.f,0.f},{0.f,0.f,0.f,0.f}};
#pragma unroll
        for (int kt = 0; kt < 8; ++kt) {
            acc[0] = __builtin_amdgcn_mfma_f32_16x16x32_bf16(af[0][kt], cur[kt], acc[0], 0, 0, 0);
            acc[1] = __builtin_amdgcn_mfma_f32_16x16x32_bf16(af[1][kt], cur[kt], acc[1], 0, 0, 0);
            acc[2] = __builtin_amdgcn_mfma_f32_16x16x32_bf16(af[2][kt], cur[kt], acc[2], 0, 0, 0);
            acc[3] = __builtin_amdgcn_mfma_f32_16x16x32_bf16(af[3][kt], cur[kt], acc[3], 0, 0, 0);
        }
        bool diag = (col0 + nt * 16 + lx) == s;
#pragma unroll
        for (int mt = 0; mt < 4; ++mt)
#pragma unroll
            for (int r = 0; r < 4; ++r) {
                float v = fmaf(acc[mt][r], w, b);
                float e = __expf(v - M);
                l[mt * 4 + r] += diag ? 0.f : e;
            }
    }

    // per-row sums: reduce over the 16 lx lanes (cols within this wave's slice)
#pragma unroll
    for (int o = 1; o < 16; o <<= 1)
#pragma unroll
        for (int i = 0; i < 16; ++i) l[i] += __shfl_xor(l[i], o);
    if (lx == 0)
#pragma unroll
        for (int mt = 0; mt < 4; ++mt)
#pragma unroll
            for (int r = 0; r < 4; ++r)
                sl[wave][mt * 16 + quad * 4 + r] = l[mt * 4 + r];
    __syncthreads();

    if (wave == 0) {   // lane = row
        float lt = sl[0][lane] + sl[1][lane] + sl[2][lane] + sl[3][lane];
        float tex = texcl[s * UTT + lane];               // fp32 diag logit
        float contrib = (M + __logf(lt + __expf(tex - M))) - tex;  // lse - target
#pragma unroll
        for (int o = 1; o < 64; o <<= 1) contrib += __shfl_xor(contrib, o);
        if (lane == 0) atomicAdd(out, contrib * (1.f / NROW));
    }
}

extern "C" void kernel_launch(void* const* d_in, const int* in_sizes, int n_in,
                              void* d_out, int out_size, void* d_ws, size_t ws_size,
                              hipStream_t stream) {
    const float* x  = (const float*)d_in[0];
    const float* wp = (const float*)d_in[1];
    const float* bp = (const float*)d_in[2];
    char* ws = (char*)d_ws;
    unsigned short* cincl = (unsigned short*)ws;                  // 512 KB
    float* texcl          = (float*)(ws + (1u << 19));            // 256 KB
    unsigned short* en    = (unsigned short*)(ws + (1u << 19) + (1u << 18)); // 32 MB
    float* out = (float*)d_out;

    hipMemsetAsync(d_out, 0, sizeof(float), stream);
    k_prep<<<SPK, 256, 0, stream>>>(x, cincl, en, texcl, wp, bp);
    k_main<<<SPK, 256, 0, stream>>>(en, cincl, texcl, wp, bp, out);
}

// Round 4
// 175.970 us; speedup vs baseline: 1.3022x; 1.0603x over previous
//
#include <hip/hip_runtime.h>

#define SPK 1024
#define UTT 64
#define DIM 256
#define EPSV 1e-5f
#define NROW (SPK * UTT)
#define NSL 8            // column slices (128 cols each)

typedef __attribute__((ext_vector_type(8))) short short8;   // 8 bf16 (4 VGPRs)
typedef __attribute__((ext_vector_type(4))) float f32x4;    // MFMA accumulator

__device__ __forceinline__ unsigned short f2bf(float f) {
    unsigned int u = __builtin_bit_cast(unsigned int, f);
    u += 0x7fffu + ((u >> 16) & 1u);          // round-to-nearest-even
    return (unsigned short)(u >> 16);
}

// K1: per-speaker column sums + inclusive centroid (bf16) + ||csum||^2.
__global__ __launch_bounds__(256)
void k_cent(const float* __restrict__ x,
            unsigned short* __restrict__ cincl,
            float* __restrict__ csum, float* __restrict__ sccv) {
    __shared__ float4 sc4[256];
    int s = blockIdx.x, tid = threadIdx.x;
    int dq = tid & 63, ug = tid >> 6;
    const float4* x4 = (const float4*)(x + (size_t)s * UTT * DIM);
    float4 p = {0.f, 0.f, 0.f, 0.f};
#pragma unroll
    for (int i = 0; i < 16; ++i) {
        float4 v = x4[(ug * 16 + i) * 64 + dq];
        p.x += v.x; p.y += v.y; p.z += v.z; p.w += v.w;
    }
    sc4[tid] = p;
    __syncthreads();
    if (tid < 64) {
        float4 a = sc4[dq], b2 = sc4[64 + dq], c = sc4[128 + dq], d = sc4[192 + dq];
        float4 cs = {a.x + b2.x + c.x + d.x, a.y + b2.y + c.y + d.y,
                     a.z + b2.z + c.z + d.z, a.w + b2.w + c.w + d.w};
        *(float4*)(csum + (size_t)s * DIM + dq * 4) = cs;
        float s2 = cs.x * cs.x + cs.y * cs.y + cs.z * cs.z + cs.w * cs.w;
#pragma unroll
        for (int o = 1; o < 64; o <<= 1) s2 += __shfl_xor(s2, o);
        if (tid == 0) sccv[s] = s2;
        // c_incl = (csum/U)/(||csum/U||+eps) == csum/(||csum|| + U*eps)
        float inv = 1.f / (sqrtf(s2) + UTT * EPSV);
        ushort4 ob = {f2bf(cs.x * inv), f2bf(cs.y * inv),
                      f2bf(cs.z * inv), f2bf(cs.w * inv)};
        *(ushort4*)(cincl + (size_t)s * DIM + dq * 4) = ob;
    }
}

// K2: e_n (bf16) + pre-scaled diagonal logit. One wave handles 8 whole rows;
// each row is one fully-coalesced float4 load (64 lanes x 16 B = the row).
__global__ __launch_bounds__(256)
void k_rows(const float* __restrict__ x, const float* __restrict__ csum,
            const float* __restrict__ sccv,
            unsigned short* __restrict__ en, float* __restrict__ texcl,
            const float* __restrict__ wp, const float* __restrict__ bp) {
    int tid = threadIdx.x, wave = tid >> 6, lane = tid & 63;
    int row0 = blockIdx.x * 32 + wave * 8;       // 8 rows/wave, same speaker
    int s = row0 >> 6;
    float w = wp[0], b = bp[0];
    float scc = sccv[s];
    float4 cv = ((const float4*)(csum + (size_t)s * DIM))[lane];
#pragma unroll
    for (int r = 0; r < 8; ++r) {
        int row = row0 + r;
        float4 xv = ((const float4*)(x + (size_t)row * DIM))[lane];
        float sx = xv.x * xv.x + xv.y * xv.y + xv.z * xv.z + xv.w * xv.w;
        float sc = xv.x * cv.x + xv.y * cv.y + xv.z * cv.z + xv.w * cv.w;
#pragma unroll
        for (int o = 1; o < 64; o <<= 1) {
            sx += __shfl_xor(sx, o);
            sc += __shfl_xor(sc, o);
        }
        float nx = sqrtf(sx);
        float inv = 1.f / (nx + EPSV);
        ushort4 ob = {f2bf(xv.x * inv), f2bf(xv.y * inv),
                      f2bf(xv.z * inv), f2bf(xv.w * inv)};
        *(ushort4*)(en + (size_t)row * DIM + lane * 4) = ob;
        if (lane == 0) {
            // sim_excl = x.(csum-x) / ((||x||+eps)(||csum-x||+63eps))
            float num = sc - sx;
            float e2 = fmaxf(scc - 2.f * sc + sx, 0.f);
            float sim = num / ((nx + EPSV) * (sqrtf(e2) + (UTT - 1) * EPSV));
            texcl[row] = fmaf(sim, w, b);
        }
    }
}

// K3: block = 4 speakers x one 128-col slice. B slice (128x256 bf16 = 64 KB)
// staged into LDS ONCE via global_load_lds (swizzled, conflict-free b128),
// one barrier, then pure ds_read+MFMA+exp. K-split accumulators -> 8
// independent MFMA chains. Partial row exp-sums -> partial[slice][row].
__global__ __launch_bounds__(256, 2)
void k_main(const unsigned short* __restrict__ en,
            const unsigned short* __restrict__ cincl,
            float* __restrict__ partial,
            const float* __restrict__ wp, const float* __restrict__ bp) {
    __shared__ unsigned short Bs[64 * 512];      // 64 slots x 1 KB = 64 KB
    int tid = threadIdx.x, wave = tid >> 6, lane = tid & 63;
    int quad = lane >> 4, lx = lane & 15;
    int cs = blockIdx.x & (NSL - 1), sg = blockIdx.x >> 3;
    int sw = sg * 4 + wave;                      // this wave's speaker
    float w = wp[0], b = bp[0];
    float M = fabsf(w) * 1.0625f + b;            // >= any logit (|sim| <= ~1)

    // stage B: slot p=(nt*8+kt): lane ℓ holds B[n=ℓ&15][k=(ℓ>>4)*8..] for tile
#pragma unroll
    for (int i = 0; i < 16; ++i) {
        int p = wave * 16 + i;
        int nt = p >> 3, kt = p & 7;
        const unsigned short* g = cincl +
            (size_t)(cs * 128 + nt * 16 + lx) * DIM + kt * 32 + quad * 8;
        __builtin_amdgcn_global_load_lds(
            (const __attribute__((address_space(1))) void*)g,
            (__attribute__((address_space(3))) void*)(Bs + p * 512), 16, 0, 0);
    }

    // A fragments (64 rows of speaker sw) while staging is in flight
    const unsigned short* abase = en + (size_t)sw * UTT * DIM;
    short8 af[4][8];
#pragma unroll
    for (int mt = 0; mt < 4; ++mt)
#pragma unroll
        for (int kt = 0; kt < 8; ++kt)
            af[mt][kt] = *(const short8*)(abase + (mt * 16 + lx) * DIM + kt * 32 + quad * 8);

    float l[16];
#pragma unroll
    for (int i = 0; i < 16; ++i) l[i] = 0.f;

    __syncthreads();

    int dnt = (sw >> 4) - cs * 8;                // diag ntile if in [0,8)
    int dlx = sw & 15;

    for (int nt = 0; nt < 8; ++nt) {
        short8 bf[8];
#pragma unroll
        for (int kt = 0; kt < 8; ++kt)
            bf[kt] = *(const short8*)(Bs + (nt * 8 + kt) * 512 + lane * 8);
        f32x4 aA[4] = {{0.f,0.f,0.f,0.f},{0.f,0.f,0.f,0.f},
                       {0.f,0.f,0.f,0.f},{0.f,0.f,0.f,0.f}};
        f32x4 aB[4] = {{0.f,0.f,0.f,0.f},{0.f,0.f,0.f,0.f},
                       {0.f,0.f,0.f,0.f},{0.f,0.f,0.f,0.f}};
#pragma unroll
        for (int kt = 0; kt < 4; ++kt) {         // 8 interleaved chains
            aA[0] = __builtin_amdgcn_mfma_f32_16x16x32_bf16(af[0][kt], bf[kt], aA[0], 0, 0, 0);
            aA[1] = __builtin_amdgcn_mfma_f32_16x16x32_bf16(af[1][kt], bf[kt], aA[1], 0, 0, 0);
            aA[2] = __builtin_amdgcn_mfma_f32_16x16x32_bf16(af[2][kt], bf[kt], aA[2], 0, 0, 0);
            aA[3] = __builtin_amdgcn_mfma_f32_16x16x32_bf16(af[3][kt], bf[kt], aA[3], 0, 0, 0);
            aB[0] = __builtin_amdgcn_mfma_f32_16x16x32_bf16(af[0][kt+4], bf[kt+4], aB[0], 0, 0, 0);
            aB[1] = __builtin_amdgcn_mfma_f32_16x16x32_bf16(af[1][kt+4], bf[kt+4], aB[1], 0, 0, 0);
            aB[2] = __builtin_amdgcn_mfma_f32_16x16x32_bf16(af[2][kt+4], bf[kt+4], aB[2], 0, 0, 0);
            aB[3] = __builtin_amdgcn_mfma_f32_16x16x32_bf16(af[3][kt+4], bf[kt+4], aB[3], 0, 0, 0);
        }
#pragma unroll
        for (int mt = 0; mt < 4; ++mt)
#pragma unroll
            for (int r = 0; r < 4; ++r) {
                float v = fmaf(aA[mt][r] + aB[mt][r], w, b);
                l[mt * 4 + r] += __expf(v - M);
            }
        if (nt == dnt) {                          // wave-uniform: undo diag col
#pragma unroll
            for (int mt = 0; mt < 4; ++mt)
#pragma unroll
                for (int r = 0; r < 4; ++r) {
                    float v = fmaf(aA[mt][r] + aB[mt][r], w, b);
                    float e = __expf(v - M);
                    if (lx == dlx) l[mt * 4 + r] -= e;
                }
        }
    }

    // reduce over the 16 col-lanes; rows live at (quad, mt, r)
#pragma unroll
    for (int o = 1; o < 16; o <<= 1)
#pragma unroll
        for (int i = 0; i < 16; ++i) l[i] += __shfl_xor(l[i], o);
    if (lx == 0)
#pragma unroll
        for (int mt = 0; mt < 4; ++mt)
#pragma unroll
            for (int r = 0; r < 4; ++r)
                partial[(size_t)cs * NROW + (size_t)sw * UTT + mt * 16 + quad * 4 + r]
                    = l[mt * 4 + r];
}

// K4: combine the 8 slice partials per row, logsumexp, mean-reduce.
__global__ __launch_bounds__(256)
void k_final(const float* __restrict__ partial, const float* __restrict__ texcl,
             const float* __restrict__ wp, const float* __restrict__ bp,
             float* __restrict__ out) {
    int row = blockIdx.x * 256 + threadIdx.x;
    float w = wp[0], b = bp[0];
    float M = fabsf(w) * 1.0625f + b;
    float t = 0.f;
#pragma unroll
    for (int sl = 0; sl < NSL; ++sl) t += partial[(size_t)sl * NROW + row];
    float tex = texcl[row];
    float c = (M + __logf(t + __expf(tex - M))) - tex;   // lse - target
#pragma unroll
    for (int o = 1; o < 64; o <<= 1) c += __shfl_xor(c, o);
    __shared__ float red[4];
    if ((threadIdx.x & 63) == 0) red[threadIdx.x >> 6] = c;
    __syncthreads();
    if (threadIdx.x == 0)
        atomicAdd(out, (red[0] + red[1] + red[2] + red[3]) * (1.f / NROW));
}

extern "C" void kernel_launch(void* const* d_in, const int* in_sizes, int n_in,
                              void* d_out, int out_size, void* d_ws, size_t ws_size,
                              hipStream_t stream) {
    const float* x  = (const float*)d_in[0];
    const float* wp = (const float*)d_in[1];
    const float* bp = (const float*)d_in[2];
    char* ws = (char*)d_ws;
    unsigned short* cincl = (unsigned short*)ws;                    // @0,   512 KB
    float* texcl          = (float*)(ws + (1u << 19));              // @512K, 256 KB
    float* csum           = (float*)(ws + (1u << 20));              // @1M,  1 MB
    float* sccv           = (float*)(ws + (2u << 20));              // @2M,  4 KB
    float* partial        = (float*)(ws + (3u << 20));              // @3M,  2 MB
    unsigned short* en    = (unsigned short*)(ws + (8u << 20));     // @8M,  32 MB
    float* out = (float*)d_out;

    hipMemsetAsync(d_out, 0, sizeof(float), stream);
    k_cent <<<SPK, 256, 0, stream>>>(x, cincl, csum, sccv);
    k_rows <<<NROW / 32, 256, 0, stream>>>(x, csum, sccv, en, texcl, wp, bp);
    k_main <<<(SPK / 4) * NSL, 256, 0, stream>>>(en, cincl, partial, wp, bp);
    k_final<<<NROW / 256, 256, 0, stream>>>(partial, texcl, wp, bp, out);
}

// Round 5
// 169.677 us; speedup vs baseline: 1.3505x; 1.0371x over previous
//
#include <hip/hip_runtime.h>

#define SPK 1024
#define UTT 64
#define DIM 256
#define EPSV 1e-5f
#define NROW (SPK * UTT)

typedef __attribute__((ext_vector_type(8))) short short8;   // 8 bf16 (4 VGPRs)
typedef __attribute__((ext_vector_type(4))) float f32x4;    // MFMA accumulator

__device__ __forceinline__ unsigned short f2bf(float f) {
    unsigned int u = __builtin_bit_cast(unsigned int, f);
    u += 0x7fffu + ((u >> 16) & 1u);          // round-to-nearest-even
    return (unsigned short)(u >> 16);
}

// K1: one block (256 thr) per speaker. Phase A: csum + c_incl (bf16) + ||csum||^2.
// Phase B: 4 lanes per row (quad-reduce), x rows cached in regs (L2-hot re-read),
// writes e_n (bf16) and pre-scaled diagonal logit texcl = w*sim_excl + b.
__global__ __launch_bounds__(256)
void k_prep(const float* __restrict__ x,
            unsigned short* __restrict__ cincl,
            unsigned short* __restrict__ en,
            float* __restrict__ texcl,
            const float* __restrict__ wp, const float* __restrict__ bp) {
    __shared__ float4 sc4[256];
    __shared__ float4 cs4[64];
    __shared__ float sccs;
    int s = blockIdx.x, tid = threadIdx.x;
    int dq = tid & 63, ug = tid >> 6;
    const float4* x4 = (const float4*)(x + (size_t)s * UTT * DIM);

    // Phase A: column sums over the 64 utterances (coalesced 1KB/instr)
    float4 p = {0.f, 0.f, 0.f, 0.f};
#pragma unroll
    for (int i = 0; i < 16; ++i) {
        float4 v = x4[(ug * 16 + i) * 64 + dq];
        p.x += v.x; p.y += v.y; p.z += v.z; p.w += v.w;
    }
    sc4[tid] = p;
    __syncthreads();
    if (tid < 64) {
        float4 a = sc4[dq], b2 = sc4[64 + dq], c = sc4[128 + dq], d = sc4[192 + dq];
        float4 cs = {a.x + b2.x + c.x + d.x, a.y + b2.y + c.y + d.y,
                     a.z + b2.z + c.z + d.z, a.w + b2.w + c.w + d.w};
        cs4[dq] = cs;
        float s2 = cs.x * cs.x + cs.y * cs.y + cs.z * cs.z + cs.w * cs.w;
#pragma unroll
        for (int o = 1; o < 64; o <<= 1) s2 += __shfl_xor(s2, o);
        if (tid == 0) sccs = s2;
        // c_incl = (csum/U)/(||csum/U||+eps) == csum/(||csum|| + U*eps)
        float inv = 1.f / (sqrtf(s2) + UTT * EPSV);
        ushort4 ob = {f2bf(cs.x * inv), f2bf(cs.y * inv),
                      f2bf(cs.z * inv), f2bf(cs.w * inv)};
        *(ushort4*)(cincl + (size_t)s * DIM + dq * 4) = ob;
    }
    __syncthreads();
    float scc = sccs;
    float w = wp[0], b = bp[0];

    // Phase B: row = tid>>2 (64 rows), sub = tid&3 (4 lanes per row).
    int row = tid >> 2, sub = tid & 3;
    const float4* xr = x4 + row * 64;
    float4 xv[16];
    float sx = 0.f, sc = 0.f;
#pragma unroll
    for (int i = 0; i < 16; ++i) {
        float4 v = xr[i * 4 + sub];
        float4 cv = cs4[i * 4 + sub];
        xv[i] = v;
        sx += v.x * v.x + v.y * v.y + v.z * v.z + v.w * v.w;
        sc += v.x * cv.x + v.y * cv.y + v.z * cv.z + v.w * cv.w;
    }
    // quad reduce: all 4 lanes of the row end up with the totals
    sx += __shfl_xor(sx, 1); sx += __shfl_xor(sx, 2);
    sc += __shfl_xor(sc, 1); sc += __shfl_xor(sc, 2);
    float nx = sqrtf(sx);
    float inv = 1.f / (nx + EPSV);
    unsigned short* er = en + (size_t)(s * UTT + row) * DIM;
#pragma unroll
    for (int i = 0; i < 16; ++i) {
        ushort4 ob = {f2bf(xv[i].x * inv), f2bf(xv[i].y * inv),
                      f2bf(xv[i].z * inv), f2bf(xv[i].w * inv)};
        *(ushort4*)(er + (i * 4 + sub) * 4) = ob;
    }
    if (sub == 0) {
        // sim_excl = x.(csum-x) / ((||x||+eps)(||csum-x||+63eps))
        float num = sc - sx;
        float e2 = fmaxf(scc - 2.f * sc + sx, 0.f);
        float sim = num / ((nx + EPSV) * (sqrtf(e2) + (UTT - 1) * EPSV));
        texcl[s * UTT + row] = fmaf(sim, w, b);
    }
}

// K2: block = 4 speakers (1 per wave), ALL 1024 cols per block -> A (en) read
// exactly once from HBM. B (cincl) staged in 16 double-buffered 64-col chunks
// (2 x 32 KB LDS) via global_load_lds, swizzled for conflict-free ds_read_b128;
// stage of chunk c+1 overlaps MFMA of chunk c. Complete rows -> in-block
// logsumexp -> one atomicAdd per wave. Fixed-max softmax (M >= any logit).
__global__ __launch_bounds__(256, 1)
void k_main(const unsigned short* __restrict__ en,
            const unsigned short* __restrict__ cincl,
            const float* __restrict__ texcl,
            const float* __restrict__ wp, const float* __restrict__ bp,
            float* __restrict__ out) {
    __shared__ unsigned short Bs[2][32 * 512];   // 2 x 32 slots x 1 KB = 64 KB
    int tid = threadIdx.x, wave = tid >> 6, lane = tid & 63;
    int quad = lane >> 4, lx = lane & 15;
    int sw = blockIdx.x * 4 + wave;              // this wave's speaker
    float w = wp[0], b = bp[0];
    float M = fabsf(w) * 1.0625f + b;            // >= any logit (|sim| <= ~1)

    // stage chunk c into buffer buf: 32 slots, slot p=(nt*8+kt), 8 per wave.
    // lane ℓ supplies B[col = c*64 + nt*16 + (ℓ&15)][k = kt*32 + (ℓ>>4)*8 ..+8]
    auto stage = [&](int c, int buf) {
#pragma unroll
        for (int i = 0; i < 8; ++i) {
            int p = wave * 8 + i;
            int nt = p >> 3, kt = p & 7;
            const unsigned short* g = cincl +
                (size_t)(c * 64 + nt * 16 + lx) * DIM + kt * 32 + quad * 8;
            __builtin_amdgcn_global_load_lds(
                (const __attribute__((address_space(1))) void*)g,
                (__attribute__((address_space(3))) void*)(&Bs[buf][p * 512]), 16, 0, 0);
        }
    };

    stage(0, 0);

    // A fragments (64 rows of speaker sw) while staging is in flight
    const unsigned short* abase = en + (size_t)sw * UTT * DIM;
    short8 af[4][8];
#pragma unroll
    for (int mt = 0; mt < 4; ++mt)
#pragma unroll
        for (int kt = 0; kt < 8; ++kt)
            af[mt][kt] = *(const short8*)(abase + (mt * 16 + lx) * DIM + kt * 32 + quad * 8);

    float l[16];
#pragma unroll
    for (int i = 0; i < 16; ++i) l[i] = 0.f;

    for (int c = 0; c < 16; ++c) {
        int buf = c & 1;
        __syncthreads();                         // stage(c) complete
        if (c < 15) stage(c + 1, buf ^ 1);       // async; hidden by compute(c)
        int dnt = (sw - c * 64) >> 4;            // diag ntile if in [0,4)
#pragma unroll
        for (int nt = 0; nt < 4; ++nt) {
            short8 bf[8];
#pragma unroll
            for (int kt = 0; kt < 8; ++kt)
                bf[kt] = *(const short8*)(&Bs[buf][(nt * 8 + kt) * 512 + lane * 8]);
            f32x4 aA[4] = {{0.f,0.f,0.f,0.f},{0.f,0.f,0.f,0.f},
                           {0.f,0.f,0.f,0.f},{0.f,0.f,0.f,0.f}};
            f32x4 aB[4] = {{0.f,0.f,0.f,0.f},{0.f,0.f,0.f,0.f},
                           {0.f,0.f,0.f,0.f},{0.f,0.f,0.f,0.f}};
#pragma unroll
            for (int kt = 0; kt < 4; ++kt) {     // 8 interleaved MFMA chains
                aA[0] = __builtin_amdgcn_mfma_f32_16x16x32_bf16(af[0][kt], bf[kt], aA[0], 0, 0, 0);
                aA[1] = __builtin_amdgcn_mfma_f32_16x16x32_bf16(af[1][kt], bf[kt], aA[1], 0, 0, 0);
                aA[2] = __builtin_amdgcn_mfma_f32_16x16x32_bf16(af[2][kt], bf[kt], aA[2], 0, 0, 0);
                aA[3] = __builtin_amdgcn_mfma_f32_16x16x32_bf16(af[3][kt], bf[kt], aA[3], 0, 0, 0);
                aB[0] = __builtin_amdgcn_mfma_f32_16x16x32_bf16(af[0][kt+4], bf[kt+4], aB[0], 0, 0, 0);
                aB[1] = __builtin_amdgcn_mfma_f32_16x16x32_bf16(af[1][kt+4], bf[kt+4], aB[1], 0, 0, 0);
                aB[2] = __builtin_amdgcn_mfma_f32_16x16x32_bf16(af[2][kt+4], bf[kt+4], aB[2], 0, 0, 0);
                aB[3] = __builtin_amdgcn_mfma_f32_16x16x32_bf16(af[3][kt+4], bf[kt+4], aB[3], 0, 0, 0);
            }
#pragma unroll
            for (int mt = 0; mt < 4; ++mt)
#pragma unroll
                for (int r = 0; r < 4; ++r) {
                    float v = fmaf(aA[mt][r] + aB[mt][r], w, b);
                    l[mt * 4 + r] += __expf(v - M);
                }
            if (nt == dnt) {                     // wave-uniform: undo diag col
#pragma unroll
                for (int mt = 0; mt < 4; ++mt)
#pragma unroll
                    for (int r = 0; r < 4; ++r) {
                        float v = fmaf(aA[mt][r] + aB[mt][r], w, b);
                        float e = __expf(v - M);
                        if (lx == (sw & 15)) l[mt * 4 + r] -= e;
                    }
            }
        }
    }

    // reduce over the 16 col-lanes; rows live at (quad, mt, r). Rows are
    // complete (all 1024 cols in this wave) -> finalize logsumexp here.
#pragma unroll
    for (int o = 1; o < 16; o <<= 1)
#pragma unroll
        for (int i = 0; i < 16; ++i) l[i] += __shfl_xor(l[i], o);

    float contrib = 0.f;
    if (lx == 0) {
#pragma unroll
        for (int mt = 0; mt < 4; ++mt)
#pragma unroll
            for (int r = 0; r < 4; ++r) {
                int row = mt * 16 + quad * 4 + r;
                float tex = texcl[sw * UTT + row];          // fp32 diag logit
                float lsum = l[mt * 4 + r] + __expf(tex - M);
                contrib += (M + __logf(lsum)) - tex;        // lse - target
            }
    }
#pragma unroll
    for (int o = 1; o < 64; o <<= 1) contrib += __shfl_xor(contrib, o);
    if (lane == 0) atomicAdd(out, contrib * (1.f / NROW));
}

extern "C" void kernel_launch(void* const* d_in, const int* in_sizes, int n_in,
                              void* d_out, int out_size, void* d_ws, size_t ws_size,
                              hipStream_t stream) {
    const float* x  = (const float*)d_in[0];
    const float* wp = (const float*)d_in[1];
    const float* bp = (const float*)d_in[2];
    char* ws = (char*)d_ws;
    unsigned short* cincl = (unsigned short*)ws;                    // @0,    512 KB
    float* texcl          = (float*)(ws + (1u << 19));              // @512K, 256 KB
    unsigned short* en    = (unsigned short*)(ws + (1u << 20));     // @1M,   32 MB
    float* out = (float*)d_out;

    hipMemsetAsync(d_out, 0, sizeof(float), stream);
    k_prep<<<SPK, 256, 0, stream>>>(x, cincl, en, texcl, wp, bp);
    k_main<<<SPK / 4, 256, 0, stream>>>(en, cincl, texcl, wp, bp, out);
}